// Round 6
// baseline (19.401 us; speedup 1.0000x reference)
//
#include <hip/hip_runtime.h>
#include <hip/hip_bf16.h>

#define BN_EPS 1e-5f

typedef float f32x4 __attribute__((ext_vector_type(4)));
typedef __bf16 bfx8 __attribute__((ext_vector_type(8)));
typedef __bf16 bfx4 __attribute__((ext_vector_type(4)));

// Dims: batch=1024, P=64, B=16, H=64, E=64, D1=512, D2=1024.
// Dead code: softmax over singleton -> aw==1 -> attention MLP + vel emb unused;
// output rows i-independent per group -> compute once per group, broadcast.
// x[r] = 0.05*[h[r], at[r]*S + wa_b]; p1 = relu(x@W1*sc1+sh1);
// p2 = relu(p1@W2*sc2+sh2); out[b*64+i] = max over group rows of p2.

// ---------------------------------------------------------------------------
// k0: blocks 0..127  : w2t[1024][512] = (bf16) W2^T
//     blocks 128..143: w1t[512][128]  = (bf16) W1^T
//     blocks 144..159: xg[1024][128]  = (bf16) 0.05*[h | at*S + wa_b]
//     block  160     : scsh = {sc1[512], sh1[512], sc2[1024], sh2[1024]}
// ---------------------------------------------------------------------------
__global__ __launch_bounds__(256) void k0_prep(
    const float* __restrict__ w2, const float* __restrict__ w1,
    const float* __restrict__ h, const float* __restrict__ at,
    const float* __restrict__ wa_w, const float* __restrict__ wa_b,
    const float* __restrict__ b1, const float* __restrict__ bn1,
    const float* __restrict__ b2, const float* __restrict__ bn2,
    __bf16* __restrict__ w2t, __bf16* __restrict__ w1t,
    __bf16* __restrict__ xg, float* __restrict__ scsh)
{
    const int t  = threadIdx.x;
    const int bx = blockIdx.x;

    if (bx < 144) {                       // transposes
        __shared__ float tile[64][69];
        int kt0, n0, src_ld, dst_ld;
        const float* src;
        __bf16* dst;
        if (bx < 128) {
            kt0 = (bx & 7) * 64;  n0 = (bx >> 3) * 64;
            src = w2; src_ld = 1024; dst = w2t; dst_ld = 512;
        } else {
            const int bt = bx - 128;
            kt0 = (bt & 1) * 64;  n0 = (bt >> 1) * 64;
            src = w1; src_ld = 512; dst = w1t; dst_ld = 128;
        }
        #pragma unroll
        for (int i = 0; i < 4; ++i) {
            const int idx = t + i * 256;
            const int kk  = idx >> 4;
            const int nq  = (idx & 15) * 4;
            const f32x4 val = *(const f32x4*)&src[(size_t)(kt0 + kk) * src_ld + n0 + nq];
            #pragma unroll
            for (int j = 0; j < 4; ++j) tile[kk][nq + j] = val[j];
        }
        __syncthreads();
        #pragma unroll
        for (int i = 0; i < 2; ++i) {
            const int idx = t + i * 256;
            const int n   = idx >> 3;
            const int kq  = (idx & 7) * 8;
            bfx8 o;
            #pragma unroll
            for (int j = 0; j < 8; ++j) o[j] = (__bf16)tile[kq + j][n];
            *(bfx8*)&dst[(size_t)(n0 + n) * dst_ld + kt0 + kq] = o;
        }
    } else if (bx < 160) {                // xg build
        __shared__ float S[64];
        const int r0 = (bx - 144) * 64;
        if (t < 64) {
            float s = 0.f;
            #pragma unroll
            for (int q = 0; q < 6; ++q) s += wa_w[q * 64 + t];
            S[t] = s;
        }
        __syncthreads();
        #pragma unroll
        for (int i = 0; i < 4; ++i) {
            const int idx = t + i * 256;          // 0..1023 bfx8 slots
            const int row = idx >> 4;
            const int cg  = (idx & 15) * 8;
            bfx8 o;
            if (cg < 64) {
                const f32x4 v0 = *(const f32x4*)&h[(size_t)(r0 + row) * 64 + cg];
                const f32x4 v1 = *(const f32x4*)&h[(size_t)(r0 + row) * 64 + cg + 4];
                #pragma unroll
                for (int j = 0; j < 4; ++j) {
                    o[j]     = (__bf16)(0.05f * v0[j]);
                    o[4 + j] = (__bf16)(0.05f * v1[j]);
                }
            } else {
                const float a = at[r0 + row];
                #pragma unroll
                for (int j = 0; j < 8; ++j) {
                    const int e = cg - 64 + j;
                    o[j] = (__bf16)(0.05f * fmaf(a, S[e], wa_b[e]));
                }
            }
            *(bfx8*)&xg[(size_t)(r0 + row) * 128 + cg] = o;
        }
    } else {                              // scale/shift folding
        for (int c = t; c < 512; c += 256) {
            const float s = rsqrtf(bn1[1536 + c] + BN_EPS) * bn1[c];
            scsh[c]       = s;
            scsh[512 + c] = (b1[c] - bn1[1024 + c]) * s + bn1[512 + c];
        }
        for (int c = t; c < 1024; c += 256) {
            const float s  = rsqrtf(bn2[3072 + c] + BN_EPS) * bn2[c];
            scsh[1024 + c] = s;
            scsh[2048 + c] = (b2[c] - bn2[2048 + c]) * s + bn2[1024 + c];
        }
    }
}

// ---------------------------------------------------------------------------
// kmain: per block (cc, b): GEMM1 (swapped, D1[c][m]) -> p1 in LDS
//        -> GEMM2 k-split (4 tiles 32x32, 2 waves/tile over k-halves)
//        -> partial combine -> max-pool -> broadcast store.
// 512 threads = 8 waves. LDS ~148 KB -> 1 block/CU.
// ---------------------------------------------------------------------------
__global__ __launch_bounds__(512, 2) void kmain(
    const __bf16* __restrict__ xg,   // [1024][128]
    const __bf16* __restrict__ w1t,  // [512][128]
    const __bf16* __restrict__ w2t,  // [1024][512]
    const float* __restrict__ scsh,  // sc1,sh1,sc2,sh2
    float* __restrict__ out)         // [1024,1024]
{
    const int cc   = blockIdx.x;
    const int b    = blockIdx.y;
    const int t    = threadIdx.x;
    const int wid  = t >> 6;
    const int lane = t & 63;
    const int l15  = lane & 15;
    const int lhi  = lane >> 4;
    const int c0w  = wid * 64;

    __shared__ __bf16 x_lds[64][136];    // [m][k]; retired -> combine scratch
    __shared__ __bf16 p1_lds[64][520];   // [m][c]
    __shared__ __bf16 B2_lds[64][520];   // [n][k]
    __shared__ float  red[2][64];

    // --- Phase 0: issue x (first), then b1r (W1T fragments); write x; barrier.
    bfx8 xfrag[2];
    #pragma unroll
    for (int i = 0; i < 2; ++i) {
        const int idx = t + i * 512;
        const int row = idx >> 4;
        const int cg  = (idx & 15) * 8;
        xfrag[i] = *(const bfx8*)&xg[(size_t)(b * 64 + row) * 128 + cg];
    }
    bfx8 b1r[16];
    #pragma unroll
    for (int ks = 0; ks < 4; ++ks)
        #pragma unroll
        for (int cf = 0; cf < 4; ++cf)
            b1r[ks * 4 + cf] = *(const bfx8*)&w1t[
                (size_t)(c0w + cf * 16 + l15) * 128 + ks * 32 + lhi * 8];
    #pragma unroll
    for (int i = 0; i < 2; ++i) {
        const int idx = t + i * 512;
        const int row = idx >> 4;
        const int cg  = (idx & 15) * 8;
        *(bfx8*)&x_lds[row][cg] = xfrag[i];
    }
    __syncthreads();

    // --- Phase 1: issue B2 panel + epilogue-1 params (hide under GEMM1)
    f32x4 b2stage[8];
    {
        const __bf16* base = w2t + (size_t)(cc * 64) * 512;
        #pragma unroll
        for (int i = 0; i < 8; ++i) {
            const int n = i * 8 + wid;
            b2stage[i] = *(const f32x4*)(base + (size_t)n * 512 + lane * 8);
        }
    }
    f32x4 sc[4], sh[4];
    #pragma unroll
    for (int cf = 0; cf < 4; ++cf) {
        const int c4 = c0w + cf * 16 + lhi * 4;
        sc[cf] = *(const f32x4*)&scsh[c4];
        sh[cf] = *(const f32x4*)&scsh[512 + c4];
    }

    // --- GEMM1 swapped: D1[c][m]; wave owns c-chunk wid*64 (b1r in regs)
    f32x4 acc1[4][4] = {};                   // [cf][mf]
    #pragma unroll
    for (int ks = 0; ks < 4; ++ks) {
        bfx8 bf_[4];
        #pragma unroll
        for (int mf = 0; mf < 4; ++mf)
            bf_[mf] = *(const bfx8*)&x_lds[mf * 16 + l15][ks * 32 + lhi * 8];
        #pragma unroll
        for (int cf = 0; cf < 4; ++cf)
            #pragma unroll
            for (int mf = 0; mf < 4; ++mf)
                acc1[cf][mf] = __builtin_amdgcn_mfma_f32_16x16x32_bf16(
                    b1r[ks * 4 + cf], bf_[mf], acc1[cf][mf], 0, 0, 0);
    }

    // --- land B2 panel (ds pipe), then epilogue-1 (VALU overlaps)
    #pragma unroll
    for (int i = 0; i < 8; ++i) {
        const int n = i * 8 + wid;
        *(f32x4*)((char*)&B2_lds[0][0] + (size_t)n * 1040 + lane * 16) =
            b2stage[i];
    }
    #pragma unroll
    for (int cf = 0; cf < 4; ++cf)
        #pragma unroll
        for (int mf = 0; mf < 4; ++mf) {
            bfx4 pk;
            #pragma unroll
            for (int r = 0; r < 4; ++r)
                pk[r] = (__bf16)fmaxf(
                    fmaf(acc1[cf][mf][r], sc[cf][r], sh[cf][r]), 0.f);
            *(bfx4*)&p1_lds[mf * 16 + l15][c0w + cf * 16 + lhi * 4] = pk;
        }
    __syncthreads();

    // --- GEMM2 k-split: tile tt = wid>>1 (32x32 at tm,tn), k-half = wid&1.
    // Per wave: 8 ks of 32, per ks 2 A + 2 B reads feed 4 MFMAs (1:1 ratio).
    const int tt    = wid >> 1;
    const int khalf = wid & 1;
    const int tm    = (tt >> 1) * 32;
    const int tn    = (tt & 1) * 32;
    const int kofs  = khalf * 256;

    float s2[2], h2[2];
    #pragma unroll
    for (int nf = 0; nf < 2; ++nf) {
        const int ng = cc * 64 + tn + nf * 16 + l15;
        s2[nf] = scsh[1024 + ng];
        h2[nf] = scsh[2048 + ng];
    }

    f32x4 acc2[2][2] = {};
    #pragma unroll
    for (int ks = 0; ks < 8; ++ks) {
        bfx8 a[2], bb[2];
        #pragma unroll
        for (int mf = 0; mf < 2; ++mf)
            a[mf] = *(const bfx8*)&p1_lds[tm + mf * 16 + l15][kofs + ks * 32 + lhi * 8];
        #pragma unroll
        for (int nf = 0; nf < 2; ++nf)
            bb[nf] = *(const bfx8*)&B2_lds[tn + nf * 16 + l15][kofs + ks * 32 + lhi * 8];
        #pragma unroll
        for (int mf = 0; mf < 2; ++mf)
            #pragma unroll
            for (int nf = 0; nf < 2; ++nf)
                acc2[mf][nf] = __builtin_amdgcn_mfma_f32_16x16x32_bf16(
                    a[mf], bb[nf], acc2[mf][nf], 0, 0, 0);
    }

    // --- combine k-halves through retired x_lds (pitch 17 -> 2-way banks)
    float* scratch = (float*)&x_lds[0][0];   // 4*64*17*4 = 17408 B, fits
    if (khalf) {
        #pragma unroll
        for (int mf = 0; mf < 2; ++mf)
            #pragma unroll
            for (int nf = 0; nf < 2; ++nf)
                *(f32x4*)&scratch[(tt * 64 + lane) * 17 + (mf * 2 + nf) * 4] =
                    acc2[mf][nf];
    }
    __syncthreads();
    if (!khalf) {
        #pragma unroll
        for (int mf = 0; mf < 2; ++mf)
            #pragma unroll
            for (int nf = 0; nf < 2; ++nf) {
                const f32x4 p =
                    *(const f32x4*)&scratch[(tt * 64 + lane) * 17 + (mf * 2 + nf) * 4];
                #pragma unroll
                for (int r = 0; r < 4; ++r) acc2[mf][nf][r] += p[r];
            }
        // epilogue-2 + pool over this tile's 32 m-rows
        #pragma unroll
        for (int nf = 0; nf < 2; ++nf) {
            float mm = 0.f;                  // relu >= 0
            #pragma unroll
            for (int mf = 0; mf < 2; ++mf)
                #pragma unroll
                for (int r = 0; r < 4; ++r)
                    mm = fmaxf(mm, fmaxf(fmaf(acc2[mf][nf][r], s2[nf], h2[nf]), 0.f));
            mm = fmaxf(mm, __shfl_xor(mm, 16));
            mm = fmaxf(mm, __shfl_xor(mm, 32));
            if (lane < 16) red[tm >> 5][tn + nf * 16 + lane] = mm;
        }
    }
    __syncthreads();

    // --- final pool over 2 m-halves + broadcast store (vectorized)
    #pragma unroll
    for (int i = 0; i < 2; ++i) {
        const int q   = t + i * 512;
        const int row = q >> 4;
        const int cq  = (q & 15) * 4;
        const f32x4 r0 = *(const f32x4*)&red[0][cq];
        const f32x4 r1 = *(const f32x4*)&red[1][cq];
        f32x4 pv;
        #pragma unroll
        for (int j = 0; j < 4; ++j)
            pv[j] = fmaxf(r0[j], r1[j]);
        *(f32x4*)&out[(size_t)(b * 64 + row) * 1024 + cc * 64 + cq] = pv;
    }
}

extern "C" void kernel_launch(void* const* d_in, const int* in_sizes, int n_in,
                              void* d_out, int out_size, void* d_ws, size_t ws_size,
                              hipStream_t stream) {
    const float* h    = (const float*)d_in[0];   // h_states  [1,1024,64]
    const float* at   = (const float*)d_in[4];   // agent_type[8,1024,1] slice 0
    const float* wa_w = (const float*)d_in[9];   // [6,64]
    const float* wa_b = (const float*)d_in[10];  // [64]
    const float* w1   = (const float*)d_in[17];  // pre1_w [128,512]
    const float* b1   = (const float*)d_in[18];  // pre1_b [512]
    const float* bn1  = (const float*)d_in[19];  // pre_bn1 [4,512]
    const float* w2   = (const float*)d_in[20];  // pre2_w [512,1024]
    const float* b2   = (const float*)d_in[21];  // pre2_b [1024]
    const float* bn2  = (const float*)d_in[22];  // pre_bn2 [4,1024]

    char* ws = (char*)d_ws;
    __bf16* w2t = (__bf16*)ws;                        // 1 MB
    __bf16* w1t = (__bf16*)(ws + (1 << 20));          // 128 KB
    __bf16* xg  = (__bf16*)(ws + (1 << 20) + (128 << 10));   // 256 KB
    float*  scsh = (float*)(ws + (1 << 20) + (384 << 10));   // 12 KB
    float*  out  = (float*)d_out;

    k0_prep<<<161, 256, 0, stream>>>(w2, w1, h, at, wa_w, wa_b,
                                     b1, bn1, b2, bn2, w2t, w1t, xg, scsh);
    kmain<<<dim3(16, 16), 512, 0, stream>>>(xg, w1t, w2t, scsh, out);
}